// Round 1
// baseline (157.754 us; speedup 1.0000x reference)
//
#include <hip/hip_runtime.h>
#include <cmath>

#define WAVE 64
#define TPB  256
#define RPW  4   // rows (or cols) per wave

__device__ __forceinline__ float giou_f(float a0, float a1, float a2, float a3, float areaA,
                                        float b0, float b1, float b2, float b3, float areaB) {
    float ltx = fmaxf(a0, b0), lty = fmaxf(a1, b1);
    float rbx = fminf(a2, b2), rby = fminf(a3, b3);
    float w = fmaxf(rbx - ltx, 0.0f), h = fmaxf(rby - lty, 0.0f);
    float inter = w * h;
    float uni = areaA + areaB - inter;
    float cx1 = fminf(a0, b0), cy1 = fminf(a1, b1);
    float cx2 = fmaxf(a2, b2), cy2 = fmaxf(a3, b3);
    float cw = fmaxf(cx2 - cx1, 0.0f), ch = fmaxf(cy2 - cy1, 0.0f);
    float areaC = cw * ch;
    return inter / uni - (areaC - uni) / areaC;
}

// ---------------- prep: cxcywh->xyxy, areas, mask->v -----------------------
__global__ void prep_kernel(const float4* __restrict__ pred, const float4* __restrict__ tgt,
                            const void* __restrict__ maskp, int M, int N,
                            float4* __restrict__ src, float* __restrict__ areaS,
                            float* __restrict__ areaT, float* __restrict__ v) {
    int m = blockIdx.x * blockDim.x + threadIdx.x;
    if (m >= M) return;
    float4 pb = pred[m];
    float x1 = pb.x - 0.5f * pb.z, y1 = pb.y - 0.5f * pb.w;
    float x2 = pb.x + 0.5f * pb.z, y2 = pb.y + 0.5f * pb.w;
    src[m] = make_float4(x1, y1, x2, y2);
    areaS[m] = (x2 - x1) * (y2 - y1);
    float4 tb = tgt[m];
    areaT[m] = (tb.z - tb.x) * (tb.w - tb.y);

    // mask layout probe: bool may arrive as u8, i32, or f32.
    const unsigned char* mb = (const unsigned char*)maskp;
    unsigned char b0 = mb[0], b1 = mb[1];
    int t = m / N;
    float vm;
    if (b0 != 0 && b1 != 0)      vm = mb[t] ? 1.0f : 0.0f;                      // u8 bool
    else if (b0 != 0)            vm = ((const int*)maskp)[t] ? 1.0f : 0.0f;     // i32
    else                         vm = (((const float*)maskp)[t] != 0.0f) ? 1.0f : 0.0f; // f32
    v[m] = vm;
}

// ---------------- row argmax: wave handles RPW rows ------------------------
__global__ void rowargmax_kernel(const float4* __restrict__ src, const float* __restrict__ areaS,
                                 const float* __restrict__ v,
                                 const float4* __restrict__ tgt, const float* __restrict__ areaT,
                                 int M, int* __restrict__ idxOut) {
    int wid  = (blockIdx.x * blockDim.x + threadIdx.x) / WAVE;
    int lane = threadIdx.x & (WAVE - 1);
    int i0 = wid * RPW;
    if (i0 >= M) return;

    float a0[RPW], a1[RPW], a2[RPW], a3[RPW], aA[RPW];
    float best[RPW];
    int   bidx[RPW];
#pragma unroll
    for (int r = 0; r < RPW; ++r) {
        int i = min(i0 + r, M - 1);
        float4 t = tgt[i];
        a0[r] = t.x; a1[r] = t.y; a2[r] = t.z; a3[r] = t.w;
        aA[r] = areaT[i];
        best[r] = -INFINITY; bidx[r] = 0;
    }

    for (int j = lane; j < M; j += WAVE) {
        float4 s = src[j];
        float aB = areaS[j];
        float vj = v[j];
#pragma unroll
        for (int r = 0; r < RPW; ++r) {
            float g = giou_f(a0[r], a1[r], a2[r], a3[r], aA[r], s.x, s.y, s.z, s.w, aB);
            float val = (vj > 0.0f) ? g : -INFINITY;
            if (val > best[r]) { best[r] = val; bidx[r] = j; }  // strict >, ascending j: first max in lane
        }
    }

#pragma unroll
    for (int r = 0; r < RPW; ++r) {
        for (int off = 32; off >= 1; off >>= 1) {
            float ov = __shfl_xor(best[r], off);
            int   oi = __shfl_xor(bidx[r], off);
            if (ov > best[r] || (ov == best[r] && oi < bidx[r])) { best[r] = ov; bidx[r] = oi; }
        }
        if (lane == 0 && (i0 + r) < M) idxOut[i0 + r] = bidx[r];
    }
}

// ---------------- column sums: wave handles RPW columns --------------------
__global__ void colsum_kernel(const float4* __restrict__ src, const float* __restrict__ areaS,
                              const float* __restrict__ v,
                              const float4* __restrict__ tgt, const float* __restrict__ areaT,
                              int M, float* __restrict__ colsum) {
    int wid  = (blockIdx.x * blockDim.x + threadIdx.x) / WAVE;
    int lane = threadIdx.x & (WAVE - 1);
    int j0 = wid * RPW;
    if (j0 >= M) return;

    float b0[RPW], b1[RPW], b2[RPW], b3[RPW], aB[RPW], acc[RPW];
#pragma unroll
    for (int r = 0; r < RPW; ++r) {
        int j = min(j0 + r, M - 1);
        float4 s = src[j];
        b0[r] = s.x; b1[r] = s.y; b2[r] = s.z; b3[r] = s.w;
        aB[r] = areaS[j];
        acc[r] = 0.0f;
    }

    for (int i = lane; i < M; i += WAVE) {
        float4 t = tgt[i];
        float aA = areaT[i];
        float vi = v[i];
#pragma unroll
        for (int r = 0; r < RPW; ++r) {
            float g = giou_f(t.x, t.y, t.z, t.w, aA, b0[r], b1[r], b2[r], b3[r], aB[r]);
            acc[r] += vi * g;
        }
    }

#pragma unroll
    for (int r = 0; r < RPW; ++r) {
        for (int off = 32; off >= 1; off >>= 1) acc[r] += __shfl_xor(acc[r], off);
        if (lane == 0 && (j0 + r) < M) colsum[j0 + r] = acc[r];
    }
}

// ---------------- final reduction (single block) ---------------------------
__device__ double block_reduce_d(double val, double* sh) {
    int tid = threadIdx.x;
    sh[tid] = val; __syncthreads();
    for (int s = TPB / 2; s > 0; s >>= 1) {
        if (tid < s) sh[tid] += sh[tid + s];
        __syncthreads();
    }
    double r = sh[0];
    __syncthreads();
    return r;
}

__global__ void final_kernel(const float4* __restrict__ src, const float4* __restrict__ tgt,
                             const float* __restrict__ v, const int* __restrict__ idx,
                             const float* __restrict__ colsum, int M, float* __restrict__ out) {
    __shared__ double sh[TPB];
    double sumV = 0.0, S1 = 0.0, S2 = 0.0, bbox = 0.0;
    for (int m = threadIdx.x; m < M; m += TPB) {
        float vi = v[m];
        int   k  = idx[m];
        float vk = v[k];
        sumV += (double)vi;
        S2   += (double)vk;
        S1   += (double)vk * (double)colsum[k];
        float4 s = src[k];
        float4 t = tgt[m];
        bbox += (double)vi * (double)(fabsf(s.x - t.x) + fabsf(s.y - t.y) +
                                      fabsf(s.z - t.z) + fabsf(s.w - t.w));
    }
    sumV = block_reduce_d(sumV, sh);
    S2   = block_reduce_d(S2, sh);
    S1   = block_reduce_d(S1, sh);
    bbox = block_reduce_d(bbox, sh);
    if (threadIdx.x == 0) {
        out[0] = (float)(1.0 - S1 / (sumV * S2));
        out[1] = (float)(bbox / (4.0 * sumV));
    }
}

// ---------------------------------------------------------------------------
extern "C" void kernel_launch(void* const* d_in, const int* in_sizes, int n_in,
                              void* d_out, int out_size, void* d_ws, size_t ws_size,
                              hipStream_t stream) {
    const float4* pred = (const float4*)d_in[0];
    const float4* tgt  = (const float4*)d_in[1];
    const void*   mask = d_in[2];

    int M = in_sizes[0] / 4;        // 4096
    int N = M / in_sizes[2];        // boxes per mask entry (8)

    // workspace layout (16B aligned)
    char* ws = (char*)d_ws;
    float4* src    = (float4*)ws;              ws += (size_t)M * 16;
    float*  areaS  = (float*)ws;               ws += (size_t)M * 4;
    float*  areaT  = (float*)ws;               ws += (size_t)M * 4;
    float*  v      = (float*)ws;               ws += (size_t)M * 4;
    float*  colsum = (float*)ws;               ws += (size_t)M * 4;
    int*    idx    = (int*)ws;                 ws += (size_t)M * 4;

    float* out = (float*)d_out;

    int prep_blocks = (M + TPB - 1) / TPB;
    prep_kernel<<<prep_blocks, TPB, 0, stream>>>(pred, tgt, mask, M, N, src, areaS, areaT, v);

    int waves   = (M + RPW - 1) / RPW;              // one wave per RPW rows/cols
    int gblocks = (waves * WAVE + TPB - 1) / TPB;
    rowargmax_kernel<<<gblocks, TPB, 0, stream>>>(src, areaS, v, tgt, areaT, M, idx);
    colsum_kernel<<<gblocks, TPB, 0, stream>>>(src, areaS, v, tgt, areaT, M, colsum);

    final_kernel<<<1, TPB, 0, stream>>>(src, tgt, v, idx, colsum, M, out);
}

// Round 2
// 105.256 us; speedup vs baseline: 1.4988x; 1.4988x over previous
//
#include <hip/hip_runtime.h>
#include <cmath>

#define WAVE 64
#define TPB  256
#define RPW  4   // rows (or cols) per wave
#define SJ   8   // chunks the inner loop is split into (occupancy knob)

__device__ __forceinline__ float fastrcp(float x) { return __builtin_amdgcn_rcpf(x); }

__device__ __forceinline__ float giou_f(float a0, float a1, float a2, float a3, float areaA,
                                        float b0, float b1, float b2, float b3, float areaB) {
    float ltx = fmaxf(a0, b0), lty = fmaxf(a1, b1);
    float rbx = fminf(a2, b2), rby = fminf(a3, b3);
    float w = fmaxf(rbx - ltx, 0.0f), h = fmaxf(rby - lty, 0.0f);
    float inter = w * h;
    float uni = areaA + areaB - inter;
    float cx1 = fminf(a0, b0), cy1 = fminf(a1, b1);
    float cx2 = fmaxf(a2, b2), cy2 = fmaxf(a3, b3);
    float areaC = (cx2 - cx1) * (cy2 - cy1);   // >=0 by construction (cx2>=cx1, cy2>=cy1)
    return inter * fastrcp(uni) - (areaC - uni) * fastrcp(areaC);
}

__device__ __forceinline__ unsigned sortable_u32(float f) {
    unsigned b = __float_as_uint(f);
    return (b & 0x80000000u) ? ~b : (b | 0x80000000u);
}

// ---------------- prep: cxcywh->xyxy, areas, mask->v -----------------------
__global__ void prep_kernel(const float4* __restrict__ pred, const float4* __restrict__ tgt,
                            const void* __restrict__ maskp, int M, int N,
                            float4* __restrict__ src, float* __restrict__ areaS,
                            float* __restrict__ areaT, float* __restrict__ v) {
    int m = blockIdx.x * blockDim.x + threadIdx.x;
    if (m >= M) return;
    float4 pb = pred[m];
    float x1 = pb.x - 0.5f * pb.z, y1 = pb.y - 0.5f * pb.w;
    float x2 = pb.x + 0.5f * pb.z, y2 = pb.y + 0.5f * pb.w;
    src[m] = make_float4(x1, y1, x2, y2);
    areaS[m] = (x2 - x1) * (y2 - y1);
    float4 tb = tgt[m];
    areaT[m] = (tb.z - tb.x) * (tb.w - tb.y);

    // mask layout probe: bool may arrive as u8, i32, or f32.
    const unsigned char* mb = (const unsigned char*)maskp;
    unsigned char b0 = mb[0], b1 = mb[1];
    int t = m / N;
    float vm;
    if (b0 != 0 && b1 != 0)      vm = mb[t] ? 1.0f : 0.0f;                      // u8 bool
    else if (b0 != 0)            vm = ((const int*)maskp)[t] ? 1.0f : 0.0f;     // i32
    else                         vm = (((const float*)maskp)[t] != 0.0f) ? 1.0f : 0.0f; // f32
    v[m] = vm;
}

// ---------------- row argmax partials: wave = RPW rows x 1 j-chunk ---------
__global__ void rowpass_kernel(const float4* __restrict__ src, const float* __restrict__ areaS,
                               const float* __restrict__ v,
                               const float4* __restrict__ tgt, const float* __restrict__ areaT,
                               int M, unsigned long long* __restrict__ keypart) {
    int wid  = (blockIdx.x * blockDim.x + threadIdx.x) / WAVE;
    int lane = threadIdx.x & (WAVE - 1);
    int rowgrp = wid / SJ;
    int c      = wid % SJ;
    int i0 = rowgrp * RPW;
    if (i0 >= M) return;
    int chunk = M / SJ;
    int jbeg = c * chunk, jend = jbeg + chunk;

    float a0[RPW], a1[RPW], a2[RPW], a3[RPW], aA[RPW];
    float best[RPW];
    int   bidx[RPW];
#pragma unroll
    for (int r = 0; r < RPW; ++r) {
        int i = min(i0 + r, M - 1);
        float4 t = tgt[i];
        a0[r] = t.x; a1[r] = t.y; a2[r] = t.z; a3[r] = t.w;
        aA[r] = areaT[i];
        best[r] = -INFINITY; bidx[r] = 0;
    }

    for (int j = jbeg + lane; j < jend; j += WAVE) {
        float4 s = src[j];
        float aB = areaS[j];
        float vj = v[j];
#pragma unroll
        for (int r = 0; r < RPW; ++r) {
            float g = giou_f(a0[r], a1[r], a2[r], a3[r], aA[r], s.x, s.y, s.z, s.w, aB);
            float val = (vj > 0.0f) ? g : -INFINITY;
            if (val > best[r]) { best[r] = val; bidx[r] = j; }  // strict >, ascending j
        }
    }

#pragma unroll
    for (int r = 0; r < RPW; ++r) {
        // pack: (sortable(value) << 32) | ~j  -> u64 max == (max value, min index)
        unsigned long long key = ((unsigned long long)sortable_u32(best[r]) << 32)
                               | (unsigned)(~bidx[r]);
        for (int off = 32; off >= 1; off >>= 1) {
            unsigned long long ok = __shfl_xor(key, off);
            key = (ok > key) ? ok : key;
        }
        if (lane == 0 && (i0 + r) < M) keypart[(size_t)c * M + (i0 + r)] = key;
    }
}

// ---------------- column-sum partials: wave = RPW cols x 1 i-chunk ---------
__global__ void colpass_kernel(const float4* __restrict__ src, const float* __restrict__ areaS,
                               const float* __restrict__ v,
                               const float4* __restrict__ tgt, const float* __restrict__ areaT,
                               int M, float* __restrict__ colpart) {
    int wid  = (blockIdx.x * blockDim.x + threadIdx.x) / WAVE;
    int lane = threadIdx.x & (WAVE - 1);
    int colgrp = wid / SJ;
    int c      = wid % SJ;
    int j0 = colgrp * RPW;
    if (j0 >= M) return;
    int chunk = M / SJ;
    int ibeg = c * chunk, iend = ibeg + chunk;

    float b0[RPW], b1[RPW], b2[RPW], b3[RPW], aB[RPW], acc[RPW];
#pragma unroll
    for (int r = 0; r < RPW; ++r) {
        int j = min(j0 + r, M - 1);
        float4 s = src[j];
        b0[r] = s.x; b1[r] = s.y; b2[r] = s.z; b3[r] = s.w;
        aB[r] = areaS[j];
        acc[r] = 0.0f;
    }

    for (int i = ibeg + lane; i < iend; i += WAVE) {
        float4 t = tgt[i];
        float aA = areaT[i];
        float vi = v[i];
#pragma unroll
        for (int r = 0; r < RPW; ++r) {
            float g = giou_f(t.x, t.y, t.z, t.w, aA, b0[r], b1[r], b2[r], b3[r], aB[r]);
            acc[r] += vi * g;
        }
    }

#pragma unroll
    for (int r = 0; r < RPW; ++r) {
        for (int off = 32; off >= 1; off >>= 1) acc[r] += __shfl_xor(acc[r], off);
        if (lane == 0 && (j0 + r) < M) colpart[(size_t)c * M + (j0 + r)] = acc[r];
    }
}

// ---------------- combine partials -----------------------------------------
__global__ void reduce_kernel(const unsigned long long* __restrict__ keypart,
                              const float* __restrict__ colpart,
                              int M, int* __restrict__ idx, float* __restrict__ colsum) {
    int m = blockIdx.x * blockDim.x + threadIdx.x;
    if (m >= M) return;
    unsigned long long k = keypart[m];
    float s = colpart[m];
#pragma unroll
    for (int c = 1; c < SJ; ++c) {
        unsigned long long kc = keypart[(size_t)c * M + m];
        k = (kc > k) ? kc : k;
        s += colpart[(size_t)c * M + m];
    }
    idx[m] = (int)(~(unsigned)k);
    colsum[m] = s;
}

// ---------------- final reduction (single block) ---------------------------
__device__ double block_reduce_d(double val, double* sh) {
    int tid = threadIdx.x;
    sh[tid] = val; __syncthreads();
    for (int s = TPB / 2; s > 0; s >>= 1) {
        if (tid < s) sh[tid] += sh[tid + s];
        __syncthreads();
    }
    double r = sh[0];
    __syncthreads();
    return r;
}

__global__ void final_kernel(const float4* __restrict__ src, const float4* __restrict__ tgt,
                             const float* __restrict__ v, const int* __restrict__ idx,
                             const float* __restrict__ colsum, int M, float* __restrict__ out) {
    __shared__ double sh[TPB];
    double sumV = 0.0, S1 = 0.0, S2 = 0.0, bbox = 0.0;
    for (int m = threadIdx.x; m < M; m += TPB) {
        float vi = v[m];
        int   k  = idx[m];
        float vk = v[k];
        sumV += (double)vi;
        S2   += (double)vk;
        S1   += (double)vk * (double)colsum[k];
        float4 s = src[k];
        float4 t = tgt[m];
        bbox += (double)vi * (double)(fabsf(s.x - t.x) + fabsf(s.y - t.y) +
                                      fabsf(s.z - t.z) + fabsf(s.w - t.w));
    }
    sumV = block_reduce_d(sumV, sh);
    S2   = block_reduce_d(S2, sh);
    S1   = block_reduce_d(S1, sh);
    bbox = block_reduce_d(bbox, sh);
    if (threadIdx.x == 0) {
        out[0] = (float)(1.0 - S1 / (sumV * S2));
        out[1] = (float)(bbox / (4.0 * sumV));
    }
}

// ---------------------------------------------------------------------------
extern "C" void kernel_launch(void* const* d_in, const int* in_sizes, int n_in,
                              void* d_out, int out_size, void* d_ws, size_t ws_size,
                              hipStream_t stream) {
    const float4* pred = (const float4*)d_in[0];
    const float4* tgt  = (const float4*)d_in[1];
    const void*   mask = d_in[2];

    int M = in_sizes[0] / 4;        // 4096
    int N = M / in_sizes[2];        // boxes per mask entry (8)

    // workspace layout (16B aligned)
    char* ws = (char*)d_ws;
    float4* src    = (float4*)ws;              ws += (size_t)M * 16;
    float*  areaS  = (float*)ws;               ws += (size_t)M * 4;
    float*  areaT  = (float*)ws;               ws += (size_t)M * 4;
    float*  v      = (float*)ws;               ws += (size_t)M * 4;
    float*  colsum = (float*)ws;               ws += (size_t)M * 4;
    int*    idx    = (int*)ws;                 ws += (size_t)M * 4;
    unsigned long long* keypart = (unsigned long long*)ws; ws += (size_t)SJ * M * 8;
    float*  colpart = (float*)ws;              ws += (size_t)SJ * M * 4;

    float* out = (float*)d_out;

    int prep_blocks = (M + TPB - 1) / TPB;
    prep_kernel<<<prep_blocks, TPB, 0, stream>>>(pred, tgt, mask, M, N, src, areaS, areaT, v);

    int waves   = ((M + RPW - 1) / RPW) * SJ;       // one wave per (RPW rows, j-chunk)
    int gblocks = (waves * WAVE + TPB - 1) / TPB;
    rowpass_kernel<<<gblocks, TPB, 0, stream>>>(src, areaS, v, tgt, areaT, M, keypart);
    colpass_kernel<<<gblocks, TPB, 0, stream>>>(src, areaS, v, tgt, areaT, M, colpart);

    reduce_kernel<<<prep_blocks, TPB, 0, stream>>>(keypart, colpart, M, idx, colsum);

    final_kernel<<<1, TPB, 0, stream>>>(src, tgt, v, idx, colsum, M, out);
}

// Round 3
// 102.195 us; speedup vs baseline: 1.5437x; 1.0299x over previous
//
#include <hip/hip_runtime.h>
#include <cmath>

#define WAVE 64
#define TPB  256
#define RPW  4   // rows (or cols) held in registers per wave
#define SJ   8   // inner-loop split (occupancy knob)
#define FTPB 1024
#define MMAX 4096

__device__ __forceinline__ float fastrcp(float x) { return __builtin_amdgcn_rcpf(x); }

__device__ __forceinline__ float giou_f(float a0, float a1, float a2, float a3, float areaA,
                                        float b0, float b1, float b2, float b3, float areaB) {
    float ltx = fmaxf(a0, b0), lty = fmaxf(a1, b1);
    float rbx = fminf(a2, b2), rby = fminf(a3, b3);
    float w = fmaxf(rbx - ltx, 0.0f), h = fmaxf(rby - lty, 0.0f);
    float inter = w * h;
    float uni = areaA + areaB - inter;
    float cx1 = fminf(a0, b0), cy1 = fminf(a1, b1);
    float cx2 = fmaxf(a2, b2), cy2 = fmaxf(a3, b3);
    float areaC = (cx2 - cx1) * (cy2 - cy1);   // >=0 by construction
    return inter * fastrcp(uni) - (areaC - uni) * fastrcp(areaC);
}

__device__ __forceinline__ unsigned sortable_u32(float f) {
    unsigned b = __float_as_uint(f);
    return (b & 0x80000000u) ? ~b : (b | 0x80000000u);
}

// mask may arrive as u8 bool, i32, or f32 — probe byte pattern once.
__device__ __forceinline__ int mask_mode(const void* maskp) {
    const unsigned char* mb = (const unsigned char*)maskp;
    unsigned char b0 = mb[0], b1 = mb[1];
    if (b0 != 0 && b1 != 0) return 0;   // u8
    if (b0 != 0) return 1;              // i32
    return 2;                           // f32
}
__device__ __forceinline__ float mask_v(const void* maskp, int t, int mode) {
    if (mode == 0) return ((const unsigned char*)maskp)[t] ? 1.0f : 0.0f;
    if (mode == 1) return ((const int*)maskp)[t] ? 1.0f : 0.0f;
    return (((const float*)maskp)[t] != 0.0f) ? 1.0f : 0.0f;
}
__device__ __forceinline__ int midx(int m, int nsh, int N) {
    return (nsh >= 0) ? (m >> nsh) : (m / N);
}

// ---------------- fused pass: row-argmax partials + col-sum partials -------
__global__ __launch_bounds__(TPB) void pass_kernel(
        const float4* __restrict__ pred, const float4* __restrict__ tgt,
        const void* __restrict__ maskp, int M, int nsh, int N,
        unsigned long long* __restrict__ keypart, float* __restrict__ colpart,
        int rowBlocks) {
    const int mode  = mask_mode(maskp);
    const int chunk = M / SJ;
    const int lane  = threadIdx.x & (WAVE - 1);
    const int warp  = threadIdx.x >> 6;

    if ((int)blockIdx.x < rowBlocks) {
        // ---- row-argmax role: registers hold RPW tgt rows; iterate src cols
        int wid = blockIdx.x * (TPB / WAVE) + warp;
        int rowgrp = wid / SJ, c = wid % SJ;
        int i0 = rowgrp * RPW;
        if (i0 >= M) return;
        int jbeg = c * chunk, jend = jbeg + chunk;

        float a0[RPW], a1[RPW], a2[RPW], a3[RPW], aA[RPW], best[RPW];
        int bidx[RPW];
#pragma unroll
        for (int r = 0; r < RPW; ++r) {
            float4 t = tgt[i0 + r];
            a0[r] = t.x; a1[r] = t.y; a2[r] = t.z; a3[r] = t.w;
            aA[r] = (t.z - t.x) * (t.w - t.y);
            best[r] = -INFINITY; bidx[r] = 0;
        }

#pragma unroll 4
        for (int j = jbeg + lane; j < jend; j += WAVE) {
            float4 p = pred[j];
            float sx1 = p.x - 0.5f * p.z, sy1 = p.y - 0.5f * p.w;
            float sx2 = p.x + 0.5f * p.z, sy2 = p.y + 0.5f * p.w;
            float aB = (sx2 - sx1) * (sy2 - sy1);
            float vj = mask_v(maskp, midx(j, nsh, N), mode);
            bool mv = vj > 0.0f;
#pragma unroll
            for (int r = 0; r < RPW; ++r) {
                float g = giou_f(a0[r], a1[r], a2[r], a3[r], aA[r], sx1, sy1, sx2, sy2, aB);
                float val = mv ? g : -INFINITY;
                if (val > best[r]) { best[r] = val; bidx[r] = j; } // strict >, ascending j
            }
        }

#pragma unroll
        for (int r = 0; r < RPW; ++r) {
            unsigned long long key = ((unsigned long long)sortable_u32(best[r]) << 32)
                                   | (unsigned)(~bidx[r]);
            for (int off = 32; off >= 1; off >>= 1) {
                unsigned long long ok = __shfl_xor(key, off);
                key = (ok > key) ? ok : key;
            }
            if (lane == 0) keypart[(size_t)c * M + (i0 + r)] = key;
        }
    } else {
        // ---- col-sum role: registers hold RPW src cols; iterate tgt rows
        int wid = (blockIdx.x - rowBlocks) * (TPB / WAVE) + warp;
        int colgrp = wid / SJ, c = wid % SJ;
        int j0 = colgrp * RPW;
        if (j0 >= M) return;
        int ibeg = c * chunk, iend = ibeg + chunk;

        float b0[RPW], b1[RPW], b2[RPW], b3[RPW], aB[RPW], acc[RPW];
#pragma unroll
        for (int r = 0; r < RPW; ++r) {
            float4 p = pred[j0 + r];
            b0[r] = p.x - 0.5f * p.z; b1[r] = p.y - 0.5f * p.w;
            b2[r] = p.x + 0.5f * p.z; b3[r] = p.y + 0.5f * p.w;
            aB[r] = (b2[r] - b0[r]) * (b3[r] - b1[r]);
            acc[r] = 0.0f;
        }

#pragma unroll 4
        for (int i = ibeg + lane; i < iend; i += WAVE) {
            float4 t = tgt[i];
            float aA = (t.z - t.x) * (t.w - t.y);
            float vi = mask_v(maskp, midx(i, nsh, N), mode);
#pragma unroll
            for (int r = 0; r < RPW; ++r) {
                float g = giou_f(t.x, t.y, t.z, t.w, aA, b0[r], b1[r], b2[r], b3[r], aB[r]);
                acc[r] += vi * g;
            }
        }

#pragma unroll
        for (int r = 0; r < RPW; ++r) {
            for (int off = 32; off >= 1; off >>= 1) acc[r] += __shfl_xor(acc[r], off);
            if (lane == 0) colpart[(size_t)c * M + (j0 + r)] = acc[r];
        }
    }
}

// ---------------- finalize: combine partials + all reductions, 1 block -----
__device__ __forceinline__ double wave_sum_d(double x) {
    for (int off = 32; off >= 1; off >>= 1) x += __shfl_xor(x, off);
    return x;
}

__global__ __launch_bounds__(FTPB) void finalize_kernel(
        const float4* __restrict__ pred, const float4* __restrict__ tgt,
        const void* __restrict__ maskp, int M, int nsh, int N,
        const unsigned long long* __restrict__ keypart,
        const float* __restrict__ colpart, float* __restrict__ out) {
    __shared__ float cs_lds[MMAX];
    __shared__ unsigned short idx_lds[MMAX];
    __shared__ float v_lds[MMAX];
    __shared__ double red[4 * (FTPB / WAVE)];

    const int mode = mask_mode(maskp);
    const int tid = threadIdx.x;

    for (int m = tid; m < M; m += FTPB) {
        unsigned long long k = keypart[m];
        float s = colpart[m];
#pragma unroll
        for (int c = 1; c < SJ; ++c) {
            unsigned long long kc = keypart[(size_t)c * M + m];
            k = (kc > k) ? kc : k;
            s += colpart[(size_t)c * M + m];
        }
        idx_lds[m] = (unsigned short)(~(unsigned)k);
        cs_lds[m] = s;
        v_lds[m] = mask_v(maskp, midx(m, nsh, N), mode);
    }
    __syncthreads();

    double sumV = 0.0, S1 = 0.0, S2 = 0.0, bbox = 0.0;
    for (int m = tid; m < M; m += FTPB) {
        float vi = v_lds[m];
        int k = idx_lds[m];
        float vk = v_lds[k];
        sumV += (double)vi;
        S2   += (double)vk;
        S1   += (double)vk * (double)cs_lds[k];
        float4 p = pred[k];
        float sx1 = p.x - 0.5f * p.z, sy1 = p.y - 0.5f * p.w;
        float sx2 = p.x + 0.5f * p.z, sy2 = p.y + 0.5f * p.w;
        float4 t = tgt[m];
        bbox += (double)vi * (double)(fabsf(sx1 - t.x) + fabsf(sy1 - t.y) +
                                      fabsf(sx2 - t.z) + fabsf(sy2 - t.w));
    }
    sumV = wave_sum_d(sumV);
    S2   = wave_sum_d(S2);
    S1   = wave_sum_d(S1);
    bbox = wave_sum_d(bbox);
    int wid = tid >> 6, lane = tid & (WAVE - 1);
    const int NW = FTPB / WAVE;
    if (lane == 0) {
        red[wid] = sumV; red[NW + wid] = S2; red[2 * NW + wid] = S1; red[3 * NW + wid] = bbox;
    }
    __syncthreads();
    if (tid == 0) {
        double a = 0, b = 0, c = 0, d = 0;
        for (int w = 0; w < NW; ++w) {
            a += red[w]; b += red[NW + w]; c += red[2 * NW + w]; d += red[3 * NW + w];
        }
        out[0] = (float)(1.0 - c / (a * b));
        out[1] = (float)(d / (4.0 * a));
    }
}

// ---------------------------------------------------------------------------
extern "C" void kernel_launch(void* const* d_in, const int* in_sizes, int n_in,
                              void* d_out, int out_size, void* d_ws, size_t ws_size,
                              hipStream_t stream) {
    const float4* pred = (const float4*)d_in[0];
    const float4* tgt  = (const float4*)d_in[1];
    const void*   mask = d_in[2];

    int M = in_sizes[0] / 4;        // 4096
    int N = M / in_sizes[2];        // boxes per mask entry (8)
    int nsh = -1;
    for (int s = 0; s < 31; ++s) if ((1 << s) == N) { nsh = s; break; }

    char* ws = (char*)d_ws;
    unsigned long long* keypart = (unsigned long long*)ws; ws += (size_t)SJ * M * 8;
    float* colpart = (float*)ws;                           ws += (size_t)SJ * M * 4;
    float* out = (float*)d_out;

    int rowBlocks = ((M / RPW) * SJ) / (TPB / WAVE);   // 2048
    int colBlocks = rowBlocks;
    pass_kernel<<<rowBlocks + colBlocks, TPB, 0, stream>>>(
        pred, tgt, mask, M, nsh, N, keypart, colpart, rowBlocks);

    finalize_kernel<<<1, FTPB, 0, stream>>>(pred, tgt, mask, M, nsh, N, keypart, colpart, out);
}